// Round 3
// baseline (632.819 us; speedup 1.0000x reference)
//
#include <hip/hip_runtime.h>

// Problem constants (match reference setup_inputs)
#define BB 128
#define HH 512
#define WW 512
#define CC 3
#define NUM_FAULTS 64

typedef int ivec4 __attribute__((ext_vector_type(4)));

// ---------------------------------------------------------------------------
// Kernel 1: bulk copy images -> out. Flat grid, 64 B per thread as 4
// independent 16 B vector loads (4 loads in flight per lane before the first
// store), coalesced 256-lane accesses. Plain loads/stores — matches the
// measured 6.29 TB/s float4-copy recipe (m13); fills on this buffer hit
// 6.33 TB/s so this is the proven path.
//
// n4 = 25,165,824 ivec4; per block: 256 threads x 4 vec = 1024 ivec4;
// grid = 24576 blocks exactly covers the buffer (no tail, no loop).
// ---------------------------------------------------------------------------
__global__ __launch_bounds__(256) void copy_kernel(const ivec4* __restrict__ in,
                                                   ivec4* __restrict__ out) {
    long base = (long)blockIdx.x * 1024 + threadIdx.x;
    ivec4 v0 = in[base];
    ivec4 v1 = in[base + 256];
    ivec4 v2 = in[base + 512];
    ivec4 v3 = in[base + 768];
    out[base]       = v0;
    out[base + 256] = v1;
    out[base + 512] = v2;
    out[base + 768] = v3;
}

// ---------------------------------------------------------------------------
// Kernel 2: apply the 64 bit faults to every image, in-place on out.
// grid = B blocks x NUM_FAULTS threads; atomicXor is exact (XOR commutes)
// even when faults collide on a pixel. 8192 atomics -> ~3 us, negligible.
// ---------------------------------------------------------------------------
__global__ __launch_bounds__(NUM_FAULTS) void fault_kernel(const int* __restrict__ faults,
                                                           int* __restrict__ out) {
    int f = threadIdx.x;   // fault index 0..63
    int b = blockIdx.x;    // batch index 0..127
    int fh = faults[4 * f + 0];
    int fw = faults[4 * f + 1];
    int fc = faults[4 * f + 2];
    int fb = faults[4 * f + 3];
    long idx = (long)b * ((long)HH * WW * CC)
             + (long)fh * (WW * CC)
             + (long)fw * CC
             + fc;
    atomicXor(&out[idx], 1 << fb);
}

extern "C" void kernel_launch(void* const* d_in, const int* in_sizes, int n_in,
                              void* d_out, int out_size, void* d_ws, size_t ws_size,
                              hipStream_t stream) {
    const int* images = (const int*)d_in[0];      // [B,H,W,C] int32
    const int* faults = (const int*)d_in[1];      // [NUM_FAULTS,4] int32
    int* out = (int*)d_out;                       // [B,H,W,C] int32

    // n = 128*512*512*3 = 100,663,296 int32 = 25,165,824 ivec4
    // 1024 ivec4 per block -> 24576 blocks, exact cover.
    copy_kernel<<<24576, 256, 0, stream>>>((const ivec4*)images, (ivec4*)out);

    fault_kernel<<<BB, NUM_FAULTS, 0, stream>>>(faults, out);
}